// Round 11
// baseline (214.249 us; speedup 1.0000x reference)
//
#include <hip/hip_runtime.h>
#include <math.h>

#define NTOK   32768
#define DIM    512
#define NTYPES 26
#define PT     128
#define NCODES 3328
#define NSAMP  312
#define INV_TEMP (1.0f / 0.07f)
#define TILES128 12   // 12*128 = 1536 >= max type count (~1400 at +4 sigma)

typedef __attribute__((ext_vector_type(8))) short short8;
typedef __attribute__((ext_vector_type(4))) float floatx4;

// split f into bf16 hi + bf16 lo (RNE both), f ~= hi + lo to ~2^-17 rel
__device__ __forceinline__ void f2bf2(float f, unsigned short& h, unsigned short& l) {
    unsigned u = __float_as_uint(f);
    unsigned hb = (u + 0x7fffu + ((u >> 16) & 1u)) >> 16;
    h = (unsigned short)hb;
    float hf = __uint_as_float(hb << 16);
    float r = f - hf;
    unsigned u2 = __float_as_uint(r);
    l = (unsigned short)((u2 + 0x7fffu + ((u2 >> 16) & 1u)) >> 16);
}

__device__ __forceinline__ void cvt8(float4 a, float4 b, short8& h, short8& l) {
    union { short8 v; unsigned short u[8]; } H, L;
    f2bf2(a.x, H.u[0], L.u[0]); f2bf2(a.y, H.u[1], L.u[1]);
    f2bf2(a.z, H.u[2], L.u[2]); f2bf2(a.w, H.u[3], L.u[3]);
    f2bf2(b.x, H.u[4], L.u[4]); f2bf2(b.y, H.u[5], L.u[5]);
    f2bf2(b.z, H.u[6], L.u[6]); f2bf2(b.w, H.u[7], L.u[7]);
    h = H.v; l = L.v;
}

// one global_load_lds dwordx4: copies 512 shorts (wave-wide) g -> lds, linear
__device__ __forceinline__ void gll1(const unsigned short* g, unsigned short* l) {
    __builtin_amdgcn_global_load_lds((const __attribute__((address_space(1))) void*)g,
                                     (__attribute__((address_space(3))) void*)l, 16, 0, 0);
}
__device__ __forceinline__ void stage2(const unsigned short* g, unsigned short* l) {
    gll1(g, l);
    gll1(g + 512, l + 512);
}

// ---------------- k_pre: fused emb precompute (blocks 0..831, 4 codes each) +
// per-block token histograms (blocks 832..959, non-atomic global writes) ------------
// emb part: bf16 hi/lo planes PRE-SWIZZLED into MFMA fragment order + sume + rinv.
// Fragment layout per type slab (65536 shorts): frag (ks2,ni) at (ks2*8+ni)*512,
// within frag lane l = q4*16+lc holds code (ni*16+lc), k = ks2*32+q4*8 .. +8.
__global__ __launch_bounds__(256) void k_pre(const float* __restrict__ emb,
                                             const int* __restrict__ Q,
                                             unsigned short* __restrict__ Bhg,
                                             unsigned short* __restrict__ Blg,
                                             float* __restrict__ sume,
                                             float* __restrict__ rinv,
                                             int* __restrict__ bhist,
                                             int* __restrict__ rankb,
                                             float* __restrict__ accg,
                                             int* __restrict__ donec) {
    int tid = threadIdx.x;
    int bid = blockIdx.x;
    if (bid < NCODES / 4) {
        if (bid == 0) {
            if (tid == 32) accg[0] = 0.0f;
            if (tid == 33) accg[1] = 0.0f;
            if (tid == 34) *donec = 0;
        }
        int wv = tid >> 6, lane = tid & 63;
        int c = bid * 4 + wv;
        const float4* row = (const float4*)(emb + (size_t)c * DIM);
        float4 v0 = row[lane * 2], v1 = row[lane * 2 + 1];   // elems k = lane*8 .. +8
        float s = v0.x*v0.x + v0.y*v0.y + v0.z*v0.z + v0.w*v0.w
                + v1.x*v1.x + v1.y*v1.y + v1.z*v1.z + v1.w*v1.w;
        for (int m = 32; m; m >>= 1) s += __shfl_xor(s, m);
        if (lane == 0) {
            sume[c] = s;
            rinv[c] = 1.0f / fmaxf(sqrtf(s), 1e-12f);
        }
        union { short8 v; unsigned short u[8]; } hh, ll;
        f2bf2(v0.x, hh.u[0], ll.u[0]); f2bf2(v0.y, hh.u[1], ll.u[1]);
        f2bf2(v0.z, hh.u[2], ll.u[2]); f2bf2(v0.w, hh.u[3], ll.u[3]);
        f2bf2(v1.x, hh.u[4], ll.u[4]); f2bf2(v1.y, hh.u[5], ll.u[5]);
        f2bf2(v1.z, hh.u[6], ll.u[6]); f2bf2(v1.w, hh.u[7], ll.u[7]);
        int qq  = c >> 7;
        int n   = c & 127;
        int ni  = n >> 4, lcc = n & 15;
        int ks2 = lane >> 2, q4d = lane & 3;
        size_t dst = (size_t)qq * (PT * DIM)
                   + (size_t)(((ks2 * 8 + ni) * 64 + q4d * 16 + lcc) * 8);
        *(short8*)(Bhg + dst) = hh.v;
        *(short8*)(Blg + dst) = ll.v;
    } else {
        __shared__ int lbin[NTYPES];
        int hb = bid - NCODES / 4;
        if (tid < NTYPES) lbin[tid] = 0;
        __syncthreads();
        int t = hb * 256 + tid;
        int q = Q[t];
        int lr = atomicAdd(&lbin[q], 1);
        __syncthreads();
        if (tid < NTYPES) bhist[hb * 32 + tid] = lbin[tid];
        rankb[t] = lr;
    }
}

// ---------------- k_scat: deterministic scatter (blocks 0..127) + normalized
// sampled-row build ne[i] = emb[samp[i]] * rinv (blocks 128..205, wave per row).
// ne is 312x512 f32 = 640KB -> fits every XCD's L2; k_uloss reads ONLY ne. ----------
__global__ __launch_bounds__(256) void k_scat(const int* __restrict__ Q,
                                              const int* __restrict__ bhist,
                                              const int* __restrict__ rankb,
                                              const float* __restrict__ emb,
                                              const float* __restrict__ rinv,
                                              const int* __restrict__ samp,
                                              int* __restrict__ order,
                                              int* __restrict__ offsg,
                                              float* __restrict__ ne) {
    int b = blockIdx.x;
    int tid = threadIdx.x;
    if (b < NTOK / 256) {
        __shared__ int offs_s[NTYPES];   // global exclusive type offsets
        __shared__ int base_s[NTYPES];   // this block's pre-sum per type
        if (tid < NTYPES) {
            int tot = 0, pre = 0;
            for (int bb = 0; bb < NTOK / 256; bb++) {
                int v = bhist[bb * 32 + tid];
                tot += v;
                if (bb < b) pre += v;
            }
            offs_s[tid] = tot;
            base_s[tid] = pre;
        }
        __syncthreads();
        if (tid == 0) {
            int a = 0;
            for (int t2 = 0; t2 < NTYPES; t2++) {
                int tt = offs_s[t2];
                offs_s[t2] = a;
                if (b == 0) offsg[t2] = a;
                a += tt;
            }
            if (b == 0) offsg[NTYPES] = a;   // = NTOK
        }
        __syncthreads();
        int t = b * 256 + tid;
        int q = Q[t];
        order[offs_s[q] + base_s[q] + rankb[t]] = t;
    } else {
        // ne-build: 78 blocks x 4 waves, wave w -> sampled row i
        int lane = tid & 63, wv = tid >> 6;
        int i = (b - NTOK / 256) * 4 + wv;           // 78*4 = 312 exactly
        int ci = samp[i];
        float rv = rinv[ci];
        const float4* er = (const float4*)(emb + (size_t)ci * DIM);
        float4 e0 = er[lane * 2], e1 = er[lane * 2 + 1];
        float4* nr = (float4*)(ne + (size_t)i * DIM);
        nr[lane * 2]     = make_float4(e0.x * rv, e0.y * rv, e0.z * rv, e0.w * rv);
        nr[lane * 2 + 1] = make_float4(e1.x * rv, e1.y * rv, e1.z * rv, e1.w * rv);
    }
}

// ---------------- main: 128tok x 128code tile (512 thr, 8 waves 4Mx2N), READ-ONLY.
// B traffic HALVED vs 64-tok tile; 1D grid with type->XCD pinning (bid&7) so each
// XCD's 3-4 type slabs (1.5-2MB) stay hot in its 4MB L2 -> B-gll = local L2 hits.
// B triple-buffered, staged 2 steps ahead via global_load_lds; A register-direct,
// depth-2 prefetch (3 rotating statically-indexed sets). Per wave per step:
// 2 B-gll + 4 A-loads -> steady wait vmcnt(6) (= st(S+1)2 + A(S+1)4 newer than
// needed st(S)/A(S)); vmcnt(0) only at step 15. ----------------
#define KSTEP(S, NSTR, AC, AF, DOSTAGE)                                          \
  {                                                                              \
    __builtin_amdgcn_sched_barrier(0);                                           \
    asm volatile("s_waitcnt vmcnt(" NSTR ")" ::: "memory");                      \
    __builtin_amdgcn_s_barrier();                                                \
    __builtin_amdgcn_sched_barrier(0);                                           \
    if (DOSTAGE) {                                                               \
      gll1(bhg + ((S) + 2) * 4096 + stoff, &Bls[((S) + 2) % 3][0][ldoff]);       \
      gll1(blg + ((S) + 2) * 4096 + stoff, &Bls[((S) + 2) % 3][1][ldoff]);       \
      AF[0] = *(const float4*)(ap0 + ((S) + 2) * 32);                            \
      AF[1] = *(const float4*)(ap0 + ((S) + 2) * 32 + 4);                        \
      AF[2] = *(const float4*)(ap1 + ((S) + 2) * 32);                            \
      AF[3] = *(const float4*)(ap1 + ((S) + 2) * 32 + 4);                        \
    }                                                                            \
    __builtin_amdgcn_sched_barrier(0);                                           \
    {                                                                            \
      float4 r0a = AC[0], r0b = AC[1], r1a = AC[2], r1b = AC[3];                 \
      ps0 = fmaf(r0a.x, r0a.x, fmaf(r0a.y, r0a.y, fmaf(r0a.z, r0a.z, fmaf(r0a.w, r0a.w, ps0)))); \
      ps0 = fmaf(r0b.x, r0b.x, fmaf(r0b.y, r0b.y, fmaf(r0b.z, r0b.z, fmaf(r0b.w, r0b.w, ps0)))); \
      ps1 = fmaf(r1a.x, r1a.x, fmaf(r1a.y, r1a.y, fmaf(r1a.z, r1a.z, fmaf(r1a.w, r1a.w, ps1)))); \
      ps1 = fmaf(r1b.x, r1b.x, fmaf(r1b.y, r1b.y, fmaf(r1b.z, r1b.z, fmaf(r1b.w, r1b.w, ps1)))); \
      short8 ah0, al0, ah1, al1;                                                 \
      cvt8(r0a, r0b, ah0, al0);                                                  \
      cvt8(r1a, r1b, ah1, al1);                                                  \
      short8 bhf[4], blf[4];                                                     \
      _Pragma("unroll")                                                          \
      for (int ni = 0; ni < 4; ni++) {                                           \
        bhf[ni] = *(const short8*)&Bls[(S) % 3][0][(wn4 + ni) * 512 + lane8];    \
        blf[ni] = *(const short8*)&Bls[(S) % 3][1][(wn4 + ni) * 512 + lane8];    \
      }                                                                          \
      _Pragma("unroll")                                                          \
      for (int ni = 0; ni < 4; ni++) {                                           \
        acc[0][ni] = __builtin_amdgcn_mfma_f32_16x16x32_bf16(ah0, bhf[ni], acc[0][ni], 0, 0, 0); \
        acc[0][ni] = __builtin_amdgcn_mfma_f32_16x16x32_bf16(ah0, blf[ni], acc[0][ni], 0, 0, 0); \
        acc[0][ni] = __builtin_amdgcn_mfma_f32_16x16x32_bf16(al0, bhf[ni], acc[0][ni], 0, 0, 0); \
        acc[1][ni] = __builtin_amdgcn_mfma_f32_16x16x32_bf16(ah1, bhf[ni], acc[1][ni], 0, 0, 0); \
        acc[1][ni] = __builtin_amdgcn_mfma_f32_16x16x32_bf16(ah1, blf[ni], acc[1][ni], 0, 0, 0); \
        acc[1][ni] = __builtin_amdgcn_mfma_f32_16x16x32_bf16(al1, bhf[ni], acc[1][ni], 0, 0, 0); \
      }                                                                          \
    }                                                                            \
  }

__global__ __launch_bounds__(512, 4) void k_main(const float* __restrict__ x,
                                                 const unsigned short* __restrict__ Bhg,
                                                 const unsigned short* __restrict__ Blg,
                                                 const int* __restrict__ order,
                                                 const int* __restrict__ offsg,
                                                 const float* __restrict__ sume,
                                                 const float* __restrict__ rinv,
                                                 float* __restrict__ idxout,
                                                 float* __restrict__ accg) {
    // type->XCD pinned decode: consecutive bids round-robin XCDs (bid&7)
    int bid = blockIdx.x;
    int xcd = bid & 7;
    int j = bid >> 3;                     // 0..47
    int jt = j / TILES128;                // which of this XCD's types
    int tile = j - jt * TILES128;
    int q = xcd + 8 * jt;
    if (q >= NTYPES) return;              // block-uniform exit, before any barrier
    int base = offsg[q];
    int cnt = offsg[q + 1] - base;
    int tstart = tile * 128;
    if (tstart >= cnt) return;
    int nt = min(128, cnt - tstart);

    __shared__ unsigned short Bls[3][2][4096];   // [buf][plane][8 frags * 512] = 48 KB
    __shared__ int   toks_s[128];
    __shared__ float sume_s[128];
    __shared__ float rinv_s[128];
    __shared__ float redv[128][2];
    __shared__ int   redi[128][2];

    int tid = threadIdx.x;
    int lane = tid & 63;
    int wv = tid >> 6;                    // 0..7
    int wm = wv & 3, wn = wv >> 2;        // 4 M-waves x 2 N-waves
    int lc = lane & 15, q4 = lane >> 4;
    int wn4 = wn * 4, lane8 = lane * 8;
    int stoff = wv * 512 + lane8;         // global src offset within a 4096-short chunk
    int ldoff = wv * 512;                 // wave-uniform LDS dest (HW adds lane*16B)

    if (tid < 128) {
        toks_s[tid] = order[base + tstart + min(tid, nt - 1)];
        sume_s[tid] = sume[q * PT + tid];
        rinv_s[tid] = rinv[q * PT + tid];
    }

    // A: this lane owns rows wm*32+lc and wm*32+16+lc (clamped tail dups last row)
    int row0 = wm * 32 + lc;
    int tok0 = order[base + tstart + min(row0, nt - 1)];
    int tok1 = order[base + tstart + min(row0 + 16, nt - 1)];
    const float* ap0 = x + (size_t)tok0 * DIM + q4 * 8;
    const float* ap1 = x + (size_t)tok1 * DIM + q4 * 8;

    const unsigned short* bhg = Bhg + (size_t)q * (PT * DIM);
    const unsigned short* blg = Blg + (size_t)q * (PT * DIM);

    floatx4 acc[2][4];
#pragma unroll
    for (int mi = 0; mi < 2; mi++)
#pragma unroll
        for (int ni = 0; ni < 4; ni++)
            acc[mi][ni] = (floatx4){0.f, 0.f, 0.f, 0.f};
    float ps0 = 0.f, ps1 = 0.f;
    float4 Aa[4], Ab[4], Ac[4];

    // prologue: st0(2), A0(4), st1(2), A1(4)  (queue oldest-first)
    gll1(bhg + stoff, &Bls[0][0][ldoff]);
    gll1(blg + stoff, &Bls[0][1][ldoff]);
    __builtin_amdgcn_sched_barrier(0);
    Aa[0] = *(const float4*)(ap0);      Aa[1] = *(const float4*)(ap0 + 4);
    Aa[2] = *(const float4*)(ap1);      Aa[3] = *(const float4*)(ap1 + 4);
    __builtin_amdgcn_sched_barrier(0);
    gll1(bhg + 4096 + stoff, &Bls[1][0][ldoff]);
    gll1(blg + 4096 + stoff, &Bls[1][1][ldoff]);
    __builtin_amdgcn_sched_barrier(0);
    Ab[0] = *(const float4*)(ap0 + 32); Ab[1] = *(const float4*)(ap0 + 36);
    Ab[2] = *(const float4*)(ap1 + 32); Ab[3] = *(const float4*)(ap1 + 36);

    // 16 K-steps; rotation: step S uses set S%3, fills set (S+2)%3 (static names).
    // Waits: S=0..14 -> vmcnt(6); S=15 -> vmcnt(0). Stage/A-issue for S<=13 only.
    KSTEP(0,  "6", Aa, Ac, 1)
    KSTEP(1,  "6", Ab, Aa, 1)
    KSTEP(2,  "6", Ac, Ab, 1)
    KSTEP(3,  "6", Aa, Ac, 1)
    KSTEP(4,  "6", Ab, Aa, 1)
    KSTEP(5,  "6", Ac, Ab, 1)
    KSTEP(6,  "6", Aa, Ac, 1)
    KSTEP(7,  "6", Ab, Aa, 1)
    KSTEP(8,  "6", Ac, Ab, 1)
    KSTEP(9,  "6", Aa, Ac, 1)
    KSTEP(10, "6", Ab, Aa, 1)
    KSTEP(11, "6", Ac, Ab, 1)
    KSTEP(12, "6", Aa, Ac, 1)
    KSTEP(13, "6", Ab, Aa, 1)
    KSTEP(14, "6", Ac, Ab, 0)
    KSTEP(15, "0", Aa, Ab, 0)

    // rnorm: sum q4-partials; every lane then holds both its rows' sums
    ps0 += __shfl_xor(ps0, 16); ps0 += __shfl_xor(ps0, 32);
    ps1 += __shfl_xor(ps1, 16); ps1 += __shfl_xor(ps1, 32);
    float rn0 = 1.0f / fmaxf(sqrtf(ps0), 1e-12f);   // row wm*32+lc
    float rn1 = 1.0f / fmaxf(sqrtf(ps1), 1e-12f);   // row wm*32+16+lc

    // argmin over this wave's 64 codes. C/D: col=lc=code%16, row=q4*4+reg
#pragma unroll
    for (int mi = 0; mi < 2; mi++) {
#pragma unroll
        for (int r = 0; r < 4; r++) {
            int rowrel = q4 * 4 + r;                       // 0..15
            float rn = __shfl(mi == 0 ? rn0 : rn1, rowrel);
            float rn2v = -2.0f * rn;
            float bv = 1e30f; int bc = 0;
#pragma unroll
            for (int ni = 0; ni < 4; ni++) {
                int n = wn * 64 + ni * 16 + lc;
                float d = fmaf(rn2v, acc[mi][ni][r], sume_s[n]);
                if (d < bv) { bv = d; bc = n; }            // n ascending: strict < keeps lowest
            }
#pragma unroll
            for (int mk = 1; mk <= 8; mk <<= 1) {          // reduce across 16-lane col group
                float ov = __shfl_xor(bv, mk);
                int oc = __shfl_xor(bc, mk);
                if (ov < bv || (ov == bv && oc < bc)) { bv = ov; bc = oc; }
            }
            int m = wm * 32 + mi * 16 + rowrel;            // 0..127
            if (lc == 0) { redv[m][wn] = bv; redi[m][wn] = bc; }
        }
    }
    __syncthreads();

    // final select per token: idx (global code) + closed-form loss row-sum 2 - 2*sim
    if (tid < 128) {
        float v0 = redv[tid][0], v1 = redv[tid][1];
        int c = (v1 < v0) ? redi[tid][1] : redi[tid][0];   // tie -> lower cols
        float bvv = fminf(v0, v1);
        float term = 0.0f;
        if (tid < nt) {
            idxout[toks_s[tid]] = (float)(q * PT + c);
            term = 2.0f - (sume_s[c] - bvv) * rinv_s[c];   // bv = sume_c - 2*rn*dot
        }
        for (int mk = 32; mk; mk >>= 1) term += __shfl_xor(term, mk);
        if (lane == 0) atomicAdd(&accg[0], term);          // 2 waves -> 2 atomics
    }
}

// ---------------- k_out: token-major SEQUENTIAL 64MB write; emb reads L2-hit.
// Each wave: 16 tokens; per token all 64 lanes write one 2KB row; emb row prefetched
// one token ahead so stores never wait on loads. ----------------
__global__ __launch_bounds__(256) void k_out(const float* __restrict__ emb,
                                             const float* __restrict__ rinv,
                                             const float* __restrict__ idxf,
                                             float* __restrict__ outbuf) {
    int tid = threadIdx.x, lane = tid & 63, wv = tid >> 6;
    int tbase = blockIdx.x * 64 + wv * 16;
    int cL = 0; float rvL = 0.f;
    if (lane < 16) {
        cL = (int)idxf[tbase + lane];
        rvL = rinv[cL];
    }
    const float4* er = (const float4*)emb;
    int c0 = __shfl(cL, 0); float rv0 = __shfl(rvL, 0);
    float4 ea = er[(size_t)c0 * 128 + lane * 2];
    float4 eb = er[(size_t)c0 * 128 + lane * 2 + 1];
#pragma unroll
    for (int t = 0; t < 16; t++) {
        float4 ca = ea, cb = eb;
        float rv = rv0;
        if (t < 15) {
            int c1 = __shfl(cL, t + 1);
            rv0 = __shfl(rvL, t + 1);
            ea = er[(size_t)c1 * 128 + lane * 2];
            eb = er[(size_t)c1 * 128 + lane * 2 + 1];
        }
        float4* orow = (float4*)(outbuf + (size_t)(tbase + t) * DIM);
        orow[lane * 2]     = make_float4(ca.x * rv, ca.y * rv, ca.z * rv, ca.w * rv);
        orow[lane * 2 + 1] = make_float4(cb.x * rv, cb.y * rv, cb.z * rv, cb.w * rv);
    }
}

// ---------------- k_uloss: reads ONLY the 640KB ne table (L2-resident on every
// XCD) -> no emb thrash, no per-dot rinv muls. Finalize folded via donec. ----------
__global__ __launch_bounds__(256) void k_uloss(const float* __restrict__ ne,
                                               const int* __restrict__ samp,
                                               float* __restrict__ accg,
                                               int* __restrict__ donec,
                                               float* __restrict__ lossp) {
    __shared__ float rs[4], rp[4];
    int i = blockIdx.x;
    int tid = threadIdx.x;
    int lane = tid & 63, wv = tid >> 6;
    int labi = samp[i] >> 7;
    const float4* ri = (const float4*)(ne + (size_t)i * DIM);
    float4 e0 = ri[lane * 2], e1 = ri[lane * 2 + 1];
    float sE = 0.0f, pE = 0.0f;
    for (int j0 = wv; j0 < NSAMP; j0 += 16) {
        float d[4]; int lj[4]; bool val[4];
#pragma unroll
        for (int u = 0; u < 4; u++) {
            int j = j0 + u * 4;
            val[u] = (j < NSAMP) && (j != i);
            int js = val[u] ? j : 0;
            lj[u] = samp[js] >> 7;
            const float4* rj = (const float4*)(ne + (size_t)js * DIM);
            float4 f0 = rj[lane * 2], f1 = rj[lane * 2 + 1];
            d[u] = e0.x*f0.x + e0.y*f0.y + e0.z*f0.z + e0.w*f0.w
                 + e1.x*f1.x + e1.y*f1.y + e1.z*f1.z + e1.w*f1.w;
        }
#pragma unroll
        for (int mk = 32; mk; mk >>= 1)
#pragma unroll
            for (int u = 0; u < 4; u++) d[u] += __shfl_xor(d[u], mk);
#pragma unroll
        for (int u = 0; u < 4; u++) {
            float ex = val[u] ? expf(d[u] * INV_TEMP) : 0.0f;
            sE += ex;
            if (val[u] && lj[u] == labi) pE += ex;
        }
    }
    if (lane == 0) { rs[wv] = sE; rp[wv] = pE; }
    __syncthreads();
    if (tid == 0) {
        float S = rs[0] + rs[1] + rs[2] + rs[3];
        float P = rp[0] + rp[1] + rp[2] + rp[3];
        atomicAdd(&accg[1], logf(S) - logf(P));
        __threadfence();
        int old = atomicAdd(donec, 1);
        if (old == NSAMP - 1) {                    // last block finalizes both scalars
            __threadfence();
            float a0 = atomicAdd(&accg[0], 0.0f);  // from k_main (stream-ordered)
            float a1 = atomicAdd(&accg[1], 0.0f);  // adds ordered before donec via fence
            lossp[0] = (1.25f / ((float)NTOK * (float)DIM)) * a0;
            lossp[1] = a1 / (float)NSAMP;
        }
    }
}

extern "C" void kernel_launch(void* const* d_in, const int* in_sizes, int n_in,
                              void* d_out, int out_size, void* d_ws, size_t ws_size,
                              hipStream_t stream) {
    const float* x   = (const float*)d_in[0];
    const float* emb = (const float*)d_in[1];
    const int* Q     = (const int*)d_in[2];
    const int* samp  = (const int*)d_in[3];

    float* out    = (float*)d_out;                       // [NTOK*DIM]
    float* lossp  = out + (size_t)NTOK * DIM;            // loss, uloss
    float* idxout = out + (size_t)NTOK * DIM + 2;        // [NTOK] idx as float

    unsigned short* Bhg = (unsigned short*)d_ws;         // NCODES*DIM bf16-hi (frag-swizzled)
    unsigned short* Blg = Bhg + (size_t)NCODES * DIM;    // NCODES*DIM bf16-lo (frag-swizzled)
    float* sume  = (float*)(Blg + (size_t)NCODES * DIM); // NCODES
    float* rinv  = sume + NCODES;                        // NCODES
    int* bhist   = (int*)(rinv + NCODES);                // 128*32
    int* rankb   = bhist + (NTOK / 256) * 32;            // NTOK
    int* offsg   = rankb + NTOK;                         // NTYPES+1 (pad 32)
    int* order   = offsg + 32;                           // NTOK
    float* ne    = (float*)(order + NTOK);               // NSAMP*DIM f32 (640KB)
    float* accg  = ne + (size_t)NSAMP * DIM;             // [2]
    int* donec   = (int*)(accg + 2);                     // [1]

    k_pre<<<NCODES / 4 + NTOK / 256, 256, 0, stream>>>(emb, Q, Bhg, Blg, sume, rinv,
                                                       bhist, rankb, accg, donec);
    k_scat<<<NTOK / 256 + NSAMP / 4, 256, 0, stream>>>(Q, bhist, rankb, emb, rinv,
                                                       samp, order, offsg, ne);
    k_main<<<8 * 4 * TILES128, 512, 0, stream>>>(x, Bhg, Blg, order, offsg, sume, rinv,
                                                 idxout, accg);
    k_out<<<NTOK / 64, 256, 0, stream>>>(emb, rinv, idxout, out);
    k_uloss<<<NSAMP, 256, 0, stream>>>(ne, samp, accg, donec, lossp);
}

// Round 12
// 197.591 us; speedup vs baseline: 1.0843x; 1.0843x over previous
//
#include <hip/hip_runtime.h>
#include <math.h>

#define NTOK   32768
#define DIM    512
#define NTYPES 26
#define PT     128
#define NCODES 3328
#define NSAMP  312
#define INV_TEMP (1.0f / 0.07f)
#define MAXTILES 24

typedef __attribute__((ext_vector_type(8))) short short8;
typedef __attribute__((ext_vector_type(4))) float floatx4;

// split f into bf16 hi + bf16 lo (RNE both), f ~= hi + lo to ~2^-17 rel
__device__ __forceinline__ void f2bf2(float f, unsigned short& h, unsigned short& l) {
    unsigned u = __float_as_uint(f);
    unsigned hb = (u + 0x7fffu + ((u >> 16) & 1u)) >> 16;
    h = (unsigned short)hb;
    float hf = __uint_as_float(hb << 16);
    float r = f - hf;
    unsigned u2 = __float_as_uint(r);
    l = (unsigned short)((u2 + 0x7fffu + ((u2 >> 16) & 1u)) >> 16);
}

__device__ __forceinline__ void cvt8(float4 a, float4 b, short8& h, short8& l) {
    union { short8 v; unsigned short u[8]; } H, L;
    f2bf2(a.x, H.u[0], L.u[0]); f2bf2(a.y, H.u[1], L.u[1]);
    f2bf2(a.z, H.u[2], L.u[2]); f2bf2(a.w, H.u[3], L.u[3]);
    f2bf2(b.x, H.u[4], L.u[4]); f2bf2(b.y, H.u[5], L.u[5]);
    f2bf2(b.z, H.u[6], L.u[6]); f2bf2(b.w, H.u[7], L.u[7]);
    h = H.v; l = L.v;
}

// 2x global_load_lds dwordx4: copies 512+512 shorts (wave-wide) g -> lds, linear
__device__ __forceinline__ void stage2(const unsigned short* g, unsigned short* l) {
    __builtin_amdgcn_global_load_lds((const __attribute__((address_space(1))) void*)g,
                                     (__attribute__((address_space(3))) void*)l, 16, 0, 0);
    __builtin_amdgcn_global_load_lds((const __attribute__((address_space(1))) void*)(g + 512),
                                     (__attribute__((address_space(3))) void*)(l + 512), 16, 0, 0);
}

// ---------------- k_pre: fused emb precompute (blocks 0..831, 4 codes each) +
// per-block token histograms (blocks 832..959, non-atomic global writes) ------------
__global__ __launch_bounds__(256) void k_pre(const float* __restrict__ emb,
                                             const int* __restrict__ Q,
                                             unsigned short* __restrict__ Bhg,
                                             unsigned short* __restrict__ Blg,
                                             float* __restrict__ sume,
                                             float* __restrict__ rinv,
                                             int* __restrict__ bhist,
                                             int* __restrict__ rankb,
                                             float* __restrict__ accg,
                                             int* __restrict__ donec) {
    int tid = threadIdx.x;
    int bid = blockIdx.x;
    if (bid < NCODES / 4) {
        if (bid == 0) {
            if (tid == 32) accg[0] = 0.0f;
            if (tid == 33) accg[1] = 0.0f;
            if (tid == 34) *donec = 0;
        }
        int wv = tid >> 6, lane = tid & 63;
        int c = bid * 4 + wv;
        const float4* row = (const float4*)(emb + (size_t)c * DIM);
        float4 v0 = row[lane * 2], v1 = row[lane * 2 + 1];   // elems k = lane*8 .. +8
        float s = v0.x*v0.x + v0.y*v0.y + v0.z*v0.z + v0.w*v0.w
                + v1.x*v1.x + v1.y*v1.y + v1.z*v1.z + v1.w*v1.w;
        for (int m = 32; m; m >>= 1) s += __shfl_xor(s, m);
        if (lane == 0) {
            sume[c] = s;
            rinv[c] = 1.0f / fmaxf(sqrtf(s), 1e-12f);
        }
        union { short8 v; unsigned short u[8]; } hh, ll;
        f2bf2(v0.x, hh.u[0], ll.u[0]); f2bf2(v0.y, hh.u[1], ll.u[1]);
        f2bf2(v0.z, hh.u[2], ll.u[2]); f2bf2(v0.w, hh.u[3], ll.u[3]);
        f2bf2(v1.x, hh.u[4], ll.u[4]); f2bf2(v1.y, hh.u[5], ll.u[5]);
        f2bf2(v1.z, hh.u[6], ll.u[6]); f2bf2(v1.w, hh.u[7], ll.u[7]);
        int qq  = c >> 7;
        int n   = c & 127;
        int ni  = n >> 4, lcc = n & 15;
        int ks2 = lane >> 2, q4d = lane & 3;
        size_t dst = (size_t)qq * (PT * DIM)
                   + (size_t)(((ks2 * 8 + ni) * 64 + q4d * 16 + lcc) * 8);
        *(short8*)(Bhg + dst) = hh.v;
        *(short8*)(Blg + dst) = ll.v;
    } else {
        __shared__ int lbin[NTYPES];
        int hb = bid - NCODES / 4;
        if (tid < NTYPES) lbin[tid] = 0;
        __syncthreads();
        int t = hb * 256 + tid;
        int q = Q[t];
        int lr = atomicAdd(&lbin[q], 1);
        __syncthreads();
        if (tid < NTYPES) bhist[hb * 32 + tid] = lbin[tid];
        rankb[t] = lr;
    }
}

// ---------------- k_scat: deterministic scatter (blocks 0..127) + normalized
// sampled-row build ne[i] = emb[samp[i]] * rinv (blocks 128..205, wave per row) -----
__global__ __launch_bounds__(256) void k_scat(const int* __restrict__ Q,
                                              const int* __restrict__ bhist,
                                              const int* __restrict__ rankb,
                                              const float* __restrict__ emb,
                                              const float* __restrict__ rinv,
                                              const int* __restrict__ samp,
                                              int* __restrict__ order,
                                              int* __restrict__ offsg,
                                              float* __restrict__ ne) {
    int b = blockIdx.x;
    int tid = threadIdx.x;
    if (b < NTOK / 256) {
        __shared__ int offs_s[NTYPES];   // global exclusive type offsets
        __shared__ int base_s[NTYPES];   // this block's pre-sum per type
        if (tid < NTYPES) {
            int tot = 0, pre = 0;
            for (int bb = 0; bb < NTOK / 256; bb++) {
                int v = bhist[bb * 32 + tid];
                tot += v;
                if (bb < b) pre += v;
            }
            offs_s[tid] = tot;
            base_s[tid] = pre;
        }
        __syncthreads();
        if (tid == 0) {
            int a = 0;
            for (int t2 = 0; t2 < NTYPES; t2++) {
                int tt = offs_s[t2];
                offs_s[t2] = a;
                if (b == 0) offsg[t2] = a;
                a += tt;
            }
            if (b == 0) offsg[NTYPES] = a;   // = NTOK
        }
        __syncthreads();
        int t = b * 256 + tid;
        int q = Q[t];
        order[offs_s[q] + base_s[q] + rankb[t]] = t;
    } else {
        // ne-build: 78 blocks x 4 waves, wave w -> sampled row i
        int lane = tid & 63, wv = tid >> 6;
        int i = (b - NTOK / 256) * 4 + wv;           // 78*4 = 312 exactly
        int ci = samp[i];
        float rv = rinv[ci];
        const float4* er = (const float4*)(emb + (size_t)ci * DIM);
        float4 e0 = er[lane * 2], e1 = er[lane * 2 + 1];
        float4* nr = (float4*)(ne + (size_t)i * DIM);
        nr[lane * 2]     = make_float4(e0.x * rv, e0.y * rv, e0.z * rv, e0.w * rv);
        nr[lane * 2 + 1] = make_float4(e1.x * rv, e1.y * rv, e1.z * rv, e1.w * rv);
    }
}

// ---------------- main: 64tok x 128code tile, 4Mx1N wave grid (NO A duplication).
// Each wave: 16 rows x 128 codes; per step per wave: 4 B-gll + 2 A-loads = 6 VM ops
// (was 8 in r10's 2Mx2N with A loaded twice). Per-block traffic 32->24 KB/step.
// B triple-buffered, staged 2 steps ahead; A register-direct depth-2 prefetch.
// Steady wait vmcnt(6) (= st(S+1)4 + A(S+1)2 newer than needed st(S)/A(S));
// vmcnt(0) only at step 15. ----------------
#define KSTEP(S, NSTR, AC, AF, DOSTAGE)                                          \
  {                                                                              \
    __builtin_amdgcn_sched_barrier(0);                                           \
    asm volatile("s_waitcnt vmcnt(" NSTR ")" ::: "memory");                      \
    __builtin_amdgcn_s_barrier();                                                \
    __builtin_amdgcn_sched_barrier(0);                                           \
    if (DOSTAGE) {                                                               \
      stage2(bhg + ((S) + 2) * 4096 + stoff, &Bls[((S) + 2) % 3][0][ldoff]);     \
      stage2(blg + ((S) + 2) * 4096 + stoff, &Bls[((S) + 2) % 3][1][ldoff]);     \
      AF[0] = *(const float4*)(ap + ((S) + 2) * 32);                             \
      AF[1] = *(const float4*)(ap + ((S) + 2) * 32 + 4);                         \
    }                                                                            \
    __builtin_amdgcn_sched_barrier(0);                                           \
    {                                                                            \
      float4 a0 = AC[0], a1 = AC[1];                                             \
      ps = fmaf(a0.x, a0.x, fmaf(a0.y, a0.y, fmaf(a0.z, a0.z, fmaf(a0.w, a0.w, ps)))); \
      ps = fmaf(a1.x, a1.x, fmaf(a1.y, a1.y, fmaf(a1.z, a1.z, fmaf(a1.w, a1.w, ps)))); \
      short8 ah, al;                                                             \
      cvt8(a0, a1, ah, al);                                                      \
      _Pragma("unroll")                                                          \
      for (int h = 0; h < 2; h++) {                                              \
        short8 bhf[4], blf[4];                                                   \
        _Pragma("unroll")                                                        \
        for (int j = 0; j < 4; j++) {                                            \
          bhf[j] = *(const short8*)&Bls[(S) % 3][0][(h * 4 + j) * 512 + lane8];  \
          blf[j] = *(const short8*)&Bls[(S) % 3][1][(h * 4 + j) * 512 + lane8];  \
        }                                                                        \
        _Pragma("unroll")                                                        \
        for (int j = 0; j < 4; j++) {                                            \
          acc[h * 4 + j] = __builtin_amdgcn_mfma_f32_16x16x32_bf16(ah, bhf[j], acc[h * 4 + j], 0, 0, 0); \
          acc[h * 4 + j] = __builtin_amdgcn_mfma_f32_16x16x32_bf16(ah, blf[j], acc[h * 4 + j], 0, 0, 0); \
          acc[h * 4 + j] = __builtin_amdgcn_mfma_f32_16x16x32_bf16(al, bhf[j], acc[h * 4 + j], 0, 0, 0); \
        }                                                                        \
      }                                                                          \
    }                                                                            \
  }

__global__ __launch_bounds__(256, 3) void k_main(const float* __restrict__ x,
                                                 const unsigned short* __restrict__ Bhg,
                                                 const unsigned short* __restrict__ Blg,
                                                 const int* __restrict__ order,
                                                 const int* __restrict__ offsg,
                                                 const float* __restrict__ sume,
                                                 const float* __restrict__ rinv,
                                                 float* __restrict__ idxout,
                                                 float* __restrict__ accg) {
    int q = blockIdx.x;
    int tile = blockIdx.y;
    int base = offsg[q];
    int cnt = offsg[q + 1] - base;
    int tstart = tile * 64;
    if (tstart >= cnt) return;            // block-uniform exit, before any barrier
    int nt = min(64, cnt - tstart);

    __shared__ unsigned short Bls[3][2][4096];   // [buf][plane][8 frags * 512] = 48 KB
    __shared__ int   toks_s[64];
    __shared__ float sume_s[128];
    __shared__ float rinv_s[128];
    __shared__ float redv[64];
    __shared__ int   redi[64];

    int tid = threadIdx.x;
    int lane = tid & 63;
    int wv = tid >> 6;                    // 0..3 = M-wave (16 rows each)
    int lc = lane & 15, q4 = lane >> 4;
    int lane8 = lane * 8;
    int stoff = wv * 1024 + lane8;        // global src offset within a 4096-short chunk
    int ldoff = wv * 1024;                // wave-uniform LDS dest (HW adds lane*16B)

    if (tid < 64) toks_s[tid] = order[base + tstart + min(tid, nt - 1)];
    if (tid < 128) {
        sume_s[tid] = sume[q * PT + tid];
        rinv_s[tid] = rinv[q * PT + tid];
    }

    // A: this lane owns row wv*16+lc, k-segment q4*8 (clamped tail dups last row)
    int rowA = wv * 16 + lc;
    int tokA = order[base + tstart + min(rowA, nt - 1)];
    const float* ap = x + (size_t)tokA * DIM + q4 * 8;

    const unsigned short* bhg = Bhg + (size_t)q * (PT * DIM);
    const unsigned short* blg = Blg + (size_t)q * (PT * DIM);

    floatx4 acc[8];
#pragma unroll
    for (int ni = 0; ni < 8; ni++) acc[ni] = (floatx4){0.f, 0.f, 0.f, 0.f};
    float ps = 0.f;
    float4 Aa[2], Ab[2], Ac[2];

    // prologue: st0(4), A0(2), st1(4), A1(2)  (queue oldest-first)
    stage2(bhg + stoff, &Bls[0][0][ldoff]);
    stage2(blg + stoff, &Bls[0][1][ldoff]);
    __builtin_amdgcn_sched_barrier(0);
    Aa[0] = *(const float4*)(ap);       Aa[1] = *(const float4*)(ap + 4);
    __builtin_amdgcn_sched_barrier(0);
    stage2(bhg + 4096 + stoff, &Bls[1][0][ldoff]);
    stage2(blg + 4096 + stoff, &Bls[1][1][ldoff]);
    __builtin_amdgcn_sched_barrier(0);
    Ab[0] = *(const float4*)(ap + 32);  Ab[1] = *(const float4*)(ap + 36);

    // 16 K-steps; rotation: step S uses set S%3, fills set (S+2)%3 (static names).
    // Waits: S=0..14 -> vmcnt(6); S=15 -> vmcnt(0). Stage/A-issue for S<=13 only.
    KSTEP(0,  "6", Aa, Ac, 1)
    KSTEP(1,  "6", Ab, Aa, 1)
    KSTEP(2,  "6", Ac, Ab, 1)
    KSTEP(3,  "6", Aa, Ac, 1)
    KSTEP(4,  "6", Ab, Aa, 1)
    KSTEP(5,  "6", Ac, Ab, 1)
    KSTEP(6,  "6", Aa, Ac, 1)
    KSTEP(7,  "6", Ab, Aa, 1)
    KSTEP(8,  "6", Ac, Ab, 1)
    KSTEP(9,  "6", Aa, Ac, 1)
    KSTEP(10, "6", Ab, Aa, 1)
    KSTEP(11, "6", Ac, Ab, 1)
    KSTEP(12, "6", Aa, Ac, 1)
    KSTEP(13, "6", Ab, Aa, 1)
    KSTEP(14, "6", Ac, Ab, 0)
    KSTEP(15, "0", Aa, Ab, 0)

    // rnorm: reduce k-segment partials; lane L then holds rn of row wv*16+(L&15)
    ps += __shfl_xor(ps, 16);
    ps += __shfl_xor(ps, 32);
    float rnv = 1.0f / fmaxf(sqrtf(ps), 1e-12f);

    // argmin over all 128 codes (this wave's 16 rows). C/D: col=lc, row=q4*4+reg
#pragma unroll
    for (int r = 0; r < 4; r++) {
        int rowrel = q4 * 4 + r;                       // 0..15
        float rn2v = -2.0f * __shfl(rnv, rowrel);
        float bv = 1e30f; int bc = 0;
#pragma unroll
        for (int ni = 0; ni < 8; ni++) {
            int n = ni * 16 + lc;
            float d = fmaf(rn2v, acc[ni][r], sume_s[n]);
            if (d < bv) { bv = d; bc = n; }            // n ascending: strict < keeps lowest
        }
#pragma unroll
        for (int mk = 1; mk <= 8; mk <<= 1) {          // reduce across 16-lane col group
            float ov = __shfl_xor(bv, mk);
            int oc = __shfl_xor(bc, mk);
            if (ov < bv || (ov == bv && oc < bc)) { bv = ov; bc = oc; }
        }
        int m = wv * 16 + rowrel;                      // 0..63
        if (lc == 0) { redv[m] = bv; redi[m] = bc; }
    }
    __syncthreads();

    // final select per token: idx (global code) + closed-form loss row-sum 2 - 2*sim
    if (tid < 64) {
        int c = redi[tid];
        float bvv = redv[tid];
        float term = 0.0f;
        if (tid < nt) {
            idxout[toks_s[tid]] = (float)(q * PT + c);
            term = 2.0f - (sume_s[c] - bvv) * rinv_s[c];   // bv = sume_c - 2*rn*dot
        }
        for (int mk = 32; mk; mk >>= 1) term += __shfl_xor(term, mk);
        if (tid == 0) atomicAdd(&accg[0], term);
    }
}

// ---------------- k_out: token-major SEQUENTIAL 64MB write; emb reads L2-hit.
__global__ __launch_bounds__(256) void k_out(const float* __restrict__ emb,
                                             const float* __restrict__ rinv,
                                             const float* __restrict__ idxf,
                                             float* __restrict__ outbuf) {
    int tid = threadIdx.x, lane = tid & 63, wv = tid >> 6;
    int tbase = blockIdx.x * 64 + wv * 16;
    int cL = 0; float rvL = 0.f;
    if (lane < 16) {
        cL = (int)idxf[tbase + lane];
        rvL = rinv[cL];
    }
    const float4* er = (const float4*)emb;
    int c0 = __shfl(cL, 0); float rv0 = __shfl(rvL, 0);
    float4 ea = er[(size_t)c0 * 128 + lane * 2];
    float4 eb = er[(size_t)c0 * 128 + lane * 2 + 1];
#pragma unroll
    for (int t = 0; t < 16; t++) {
        float4 ca = ea, cb = eb;
        float rv = rv0;
        if (t < 15) {
            int c1 = __shfl(cL, t + 1);
            rv0 = __shfl(rvL, t + 1);
            ea = er[(size_t)c1 * 128 + lane * 2];
            eb = er[(size_t)c1 * 128 + lane * 2 + 1];
        }
        float4* orow = (float4*)(outbuf + (size_t)(tbase + t) * DIM);
        orow[lane * 2]     = make_float4(ca.x * rv, ca.y * rv, ca.z * rv, ca.w * rv);
        orow[lane * 2 + 1] = make_float4(cb.x * rv, cb.y * rv, cb.z * rv, cb.w * rv);
    }
}

// ---------------- k_uloss: reads ONLY the 640KB ne table; finalize via donec ------
__global__ __launch_bounds__(256) void k_uloss(const float* __restrict__ ne,
                                               const int* __restrict__ samp,
                                               float* __restrict__ accg,
                                               int* __restrict__ donec,
                                               float* __restrict__ lossp) {
    __shared__ float rs[4], rp[4];
    int i = blockIdx.x;
    int tid = threadIdx.x;
    int lane = tid & 63, wv = tid >> 6;
    int labi = samp[i] >> 7;
    const float4* ri = (const float4*)(ne + (size_t)i * DIM);
    float4 e0 = ri[lane * 2], e1 = ri[lane * 2 + 1];
    float sE = 0.0f, pE = 0.0f;
    for (int j0 = wv; j0 < NSAMP; j0 += 16) {
        float d[4]; int lj[4]; bool val[4];
#pragma unroll
        for (int u = 0; u < 4; u++) {
            int j = j0 + u * 4;
            val[u] = (j < NSAMP) && (j != i);
            int js = val[u] ? j : 0;
            lj[u] = samp[js] >> 7;
            const float4* rj = (const float4*)(ne + (size_t)js * DIM);
            float4 f0 = rj[lane * 2], f1 = rj[lane * 2 + 1];
            d[u] = e0.x*f0.x + e0.y*f0.y + e0.z*f0.z + e0.w*f0.w
                 + e1.x*f1.x + e1.y*f1.y + e1.z*f1.z + e1.w*f1.w;
        }
#pragma unroll
        for (int mk = 32; mk; mk >>= 1)
#pragma unroll
            for (int u = 0; u < 4; u++) d[u] += __shfl_xor(d[u], mk);
#pragma unroll
        for (int u = 0; u < 4; u++) {
            float ex = val[u] ? expf(d[u] * INV_TEMP) : 0.0f;
            sE += ex;
            if (val[u] && lj[u] == labi) pE += ex;
        }
    }
    if (lane == 0) { rs[wv] = sE; rp[wv] = pE; }
    __syncthreads();
    if (tid == 0) {
        float S = rs[0] + rs[1] + rs[2] + rs[3];
        float P = rp[0] + rp[1] + rp[2] + rp[3];
        atomicAdd(&accg[1], logf(S) - logf(P));
        __threadfence();
        int old = atomicAdd(donec, 1);
        if (old == NSAMP - 1) {                    // last block finalizes both scalars
            __threadfence();
            float a0 = atomicAdd(&accg[0], 0.0f);  // from k_main (stream-ordered)
            float a1 = atomicAdd(&accg[1], 0.0f);  // adds ordered before donec via fence
            lossp[0] = (1.25f / ((float)NTOK * (float)DIM)) * a0;
            lossp[1] = a1 / (float)NSAMP;
        }
    }
}

extern "C" void kernel_launch(void* const* d_in, const int* in_sizes, int n_in,
                              void* d_out, int out_size, void* d_ws, size_t ws_size,
                              hipStream_t stream) {
    const float* x   = (const float*)d_in[0];
    const float* emb = (const float*)d_in[1];
    const int* Q     = (const int*)d_in[2];
    const int* samp  = (const int*)d_in[3];

    float* out    = (float*)d_out;                       // [NTOK*DIM]
    float* lossp  = out + (size_t)NTOK * DIM;            // loss, uloss
    float* idxout = out + (size_t)NTOK * DIM + 2;        // [NTOK] idx as float

    unsigned short* Bhg = (unsigned short*)d_ws;         // NCODES*DIM bf16-hi (frag-swizzled)
    unsigned short* Blg = Bhg + (size_t)NCODES * DIM;    // NCODES*DIM bf16-lo (frag-swizzled)
    float* sume  = (float*)(Blg + (size_t)NCODES * DIM); // NCODES
    float* rinv  = sume + NCODES;                        // NCODES
    int* bhist   = (int*)(rinv + NCODES);                // 128*32
    int* rankb   = bhist + (NTOK / 256) * 32;            // NTOK
    int* offsg   = rankb + NTOK;                         // NTYPES+1 (pad 32)
    int* order   = offsg + 32;                           // NTOK
    float* ne    = (float*)(order + NTOK);               // NSAMP*DIM f32 (640KB)
    float* accg  = ne + (size_t)NSAMP * DIM;             // [2]
    int* donec   = (int*)(accg + 2);                     // [1]

    k_pre<<<NCODES / 4 + NTOK / 256, 256, 0, stream>>>(emb, Q, Bhg, Blg, sume, rinv,
                                                       bhist, rankb, accg, donec);
    k_scat<<<NTOK / 256 + NSAMP / 4, 256, 0, stream>>>(Q, bhist, rankb, emb, rinv,
                                                       samp, order, offsg, ne);
    dim3 gmain(NTYPES, MAXTILES);
    k_main<<<gmain, 256, 0, stream>>>(x, Bhg, Blg, order, offsg, sume, rinv,
                                      idxout, accg);
    k_out<<<NTOK / 64, 256, 0, stream>>>(emb, rinv, idxout, out);
    k_uloss<<<NSAMP, 256, 0, stream>>>(ne, samp, accg, donec, lossp);
}

// Round 14
// 193.870 us; speedup vs baseline: 1.1051x; 1.0192x over previous
//
#include <hip/hip_runtime.h>
#include <math.h>

#define NTOK   32768
#define DIM    512
#define NTYPES 26
#define PT     128
#define NCODES 3328
#define NSAMP  312
#define INV_TEMP (1.0f / 0.07f)
#define MAXTILES 24

typedef __attribute__((ext_vector_type(8))) short short8;
typedef __attribute__((ext_vector_type(4))) float floatx4;

// split f into bf16 hi + bf16 lo (RNE both), f ~= hi + lo to ~2^-17 rel
__device__ __forceinline__ void f2bf2(float f, unsigned short& h, unsigned short& l) {
    unsigned u = __float_as_uint(f);
    unsigned hb = (u + 0x7fffu + ((u >> 16) & 1u)) >> 16;
    h = (unsigned short)hb;
    float hf = __uint_as_float(hb << 16);
    float r = f - hf;
    unsigned u2 = __float_as_uint(r);
    l = (unsigned short)((u2 + 0x7fffu + ((u2 >> 16) & 1u)) >> 16);
}

__device__ __forceinline__ void cvt8(float4 a, float4 b, short8& h, short8& l) {
    union { short8 v; unsigned short u[8]; } H, L;
    f2bf2(a.x, H.u[0], L.u[0]); f2bf2(a.y, H.u[1], L.u[1]);
    f2bf2(a.z, H.u[2], L.u[2]); f2bf2(a.w, H.u[3], L.u[3]);
    f2bf2(b.x, H.u[4], L.u[4]); f2bf2(b.y, H.u[5], L.u[5]);
    f2bf2(b.z, H.u[6], L.u[6]); f2bf2(b.w, H.u[7], L.u[7]);
    h = H.v; l = L.v;
}

// 2x global_load_lds dwordx4: copies 512+512 shorts (wave-wide) g -> lds, linear
__device__ __forceinline__ void stage2(const unsigned short* g, unsigned short* l) {
    __builtin_amdgcn_global_load_lds((const __attribute__((address_space(1))) void*)g,
                                     (__attribute__((address_space(3))) void*)l, 16, 0, 0);
    __builtin_amdgcn_global_load_lds((const __attribute__((address_space(1))) void*)(g + 512),
                                     (__attribute__((address_space(3))) void*)(l + 512), 16, 0, 0);
}

// ---------------- k_pre: fused emb precompute (blocks 0..831, 4 codes each) +
// per-block token histograms (blocks 832..959, non-atomic global writes) ------------
__global__ __launch_bounds__(256) void k_pre(const float* __restrict__ emb,
                                             const int* __restrict__ Q,
                                             unsigned short* __restrict__ Bhg,
                                             unsigned short* __restrict__ Blg,
                                             float* __restrict__ sume,
                                             float* __restrict__ rinv,
                                             int* __restrict__ bhist,
                                             int* __restrict__ rankb,
                                             float* __restrict__ accg,
                                             int* __restrict__ donec) {
    int tid = threadIdx.x;
    int bid = blockIdx.x;
    if (bid < NCODES / 4) {
        if (bid == 0) {
            if (tid == 32) accg[0] = 0.0f;
            if (tid == 33) accg[1] = 0.0f;
            if (tid == 34) *donec = 0;
        }
        int wv = tid >> 6, lane = tid & 63;
        int c = bid * 4 + wv;
        const float4* row = (const float4*)(emb + (size_t)c * DIM);
        float4 v0 = row[lane * 2], v1 = row[lane * 2 + 1];   // elems k = lane*8 .. +8
        float s = v0.x*v0.x + v0.y*v0.y + v0.z*v0.z + v0.w*v0.w
                + v1.x*v1.x + v1.y*v1.y + v1.z*v1.z + v1.w*v1.w;
        for (int m = 32; m; m >>= 1) s += __shfl_xor(s, m);
        if (lane == 0) {
            sume[c] = s;
            rinv[c] = 1.0f / fmaxf(sqrtf(s), 1e-12f);
        }
        union { short8 v; unsigned short u[8]; } hh, ll;
        f2bf2(v0.x, hh.u[0], ll.u[0]); f2bf2(v0.y, hh.u[1], ll.u[1]);
        f2bf2(v0.z, hh.u[2], ll.u[2]); f2bf2(v0.w, hh.u[3], ll.u[3]);
        f2bf2(v1.x, hh.u[4], ll.u[4]); f2bf2(v1.y, hh.u[5], ll.u[5]);
        f2bf2(v1.z, hh.u[6], ll.u[6]); f2bf2(v1.w, hh.u[7], ll.u[7]);
        int qq  = c >> 7;
        int n   = c & 127;
        int ni  = n >> 4, lcc = n & 15;
        int ks2 = lane >> 2, q4d = lane & 3;
        size_t dst = (size_t)qq * (PT * DIM)
                   + (size_t)(((ks2 * 8 + ni) * 64 + q4d * 16 + lcc) * 8);
        *(short8*)(Bhg + dst) = hh.v;
        *(short8*)(Blg + dst) = ll.v;
    } else {
        __shared__ int lbin[NTYPES];
        int hb = bid - NCODES / 4;
        if (tid < NTYPES) lbin[tid] = 0;
        __syncthreads();
        int t = hb * 256 + tid;
        int q = Q[t];
        int lr = atomicAdd(&lbin[q], 1);
        __syncthreads();
        if (tid < NTYPES) bhist[hb * 32 + tid] = lbin[tid];
        rankb[t] = lr;
    }
}

// ---------------- k_scat: deterministic scatter (blocks 0..127) + normalized
// sampled-row build ne[i] = emb[samp[i]] * rinv (blocks 128..205, wave per row) -----
__global__ __launch_bounds__(256) void k_scat(const int* __restrict__ Q,
                                              const int* __restrict__ bhist,
                                              const int* __restrict__ rankb,
                                              const float* __restrict__ emb,
                                              const float* __restrict__ rinv,
                                              const int* __restrict__ samp,
                                              int* __restrict__ order,
                                              int* __restrict__ offsg,
                                              float* __restrict__ ne) {
    int b = blockIdx.x;
    int tid = threadIdx.x;
    if (b < NTOK / 256) {
        __shared__ int offs_s[NTYPES];   // global exclusive type offsets
        __shared__ int base_s[NTYPES];   // this block's pre-sum per type
        if (tid < NTYPES) {
            int tot = 0, pre = 0;
            for (int bb = 0; bb < NTOK / 256; bb++) {
                int v = bhist[bb * 32 + tid];
                tot += v;
                if (bb < b) pre += v;
            }
            offs_s[tid] = tot;
            base_s[tid] = pre;
        }
        __syncthreads();
        if (tid == 0) {
            int a = 0;
            for (int t2 = 0; t2 < NTYPES; t2++) {
                int tt = offs_s[t2];
                offs_s[t2] = a;
                if (b == 0) offsg[t2] = a;
                a += tt;
            }
            if (b == 0) offsg[NTYPES] = a;   // = NTOK
        }
        __syncthreads();
        int t = b * 256 + tid;
        int q = Q[t];
        order[offs_s[q] + base_s[q] + rankb[t]] = t;
    } else {
        // ne-build: 78 blocks x 4 waves, wave w -> sampled row i
        int lane = tid & 63, wv = tid >> 6;
        int i = (b - NTOK / 256) * 4 + wv;           // 78*4 = 312 exactly
        int ci = samp[i];
        float rv = rinv[ci];
        const float4* er = (const float4*)(emb + (size_t)ci * DIM);
        float4 e0 = er[lane * 2], e1 = er[lane * 2 + 1];
        float4* nr = (float4*)(ne + (size_t)i * DIM);
        nr[lane * 2]     = make_float4(e0.x * rv, e0.y * rv, e0.z * rv, e0.w * rv);
        nr[lane * 2 + 1] = make_float4(e1.x * rv, e1.y * rv, e1.z * rv, e1.w * rv);
    }
}

// ---------------- main: 64tok x 128code tile, 4Mx1N wave grid (r12 winner) with
// A prefetch deepened to DEPTH-3 (4 rotating statically-named reg sets).
// Per step per wave: push B(S+2) [4 gll] then A(S+3) [2 loads] = 6 VM ops.
// FIFO at wait(S): [A(S),B(S),A(S+1),B(S+1),A(S+2)] = 14 -> steady vmcnt(8)
// completes A(S),B(S); tail waits 8/6/0. B stage for S<=13, A load for S<=12. ------
#define KSTEP(S, NSTR, AC, AF, DOB, DOA)                                         \
  {                                                                              \
    __builtin_amdgcn_sched_barrier(0);                                           \
    asm volatile("s_waitcnt vmcnt(" NSTR ")" ::: "memory");                      \
    __builtin_amdgcn_s_barrier();                                                \
    __builtin_amdgcn_sched_barrier(0);                                           \
    if (DOB) {                                                                   \
      stage2(bhg + ((S) + 2) * 4096 + stoff, &Bls[((S) + 2) % 3][0][ldoff]);     \
      stage2(blg + ((S) + 2) * 4096 + stoff, &Bls[((S) + 2) % 3][1][ldoff]);     \
    }                                                                            \
    if (DOA) {                                                                   \
      AF[0] = *(const float4*)(ap + ((S) + 3) * 32);                             \
      AF[1] = *(const float4*)(ap + ((S) + 3) * 32 + 4);                         \
    }                                                                            \
    __builtin_amdgcn_sched_barrier(0);                                           \
    {                                                                            \
      float4 a0 = AC[0], a1 = AC[1];                                             \
      ps = fmaf(a0.x, a0.x, fmaf(a0.y, a0.y, fmaf(a0.z, a0.z, fmaf(a0.w, a0.w, ps)))); \
      ps = fmaf(a1.x, a1.x, fmaf(a1.y, a1.y, fmaf(a1.z, a1.z, fmaf(a1.w, a1.w, ps)))); \
      short8 ah, al;                                                             \
      cvt8(a0, a1, ah, al);                                                      \
      _Pragma("unroll")                                                          \
      for (int h = 0; h < 2; h++) {                                              \
        short8 bhf[4], blf[4];                                                   \
        _Pragma("unroll")                                                        \
        for (int j = 0; j < 4; j++) {                                            \
          bhf[j] = *(const short8*)&Bls[(S) % 3][0][(h * 4 + j) * 512 + lane8];  \
          blf[j] = *(const short8*)&Bls[(S) % 3][1][(h * 4 + j) * 512 + lane8];  \
        }                                                                        \
        _Pragma("unroll")                                                        \
        for (int j = 0; j < 4; j++) {                                            \
          acc[h * 4 + j] = __builtin_amdgcn_mfma_f32_16x16x32_bf16(ah, bhf[j], acc[h * 4 + j], 0, 0, 0); \
          acc[h * 4 + j] = __builtin_amdgcn_mfma_f32_16x16x32_bf16(ah, blf[j], acc[h * 4 + j], 0, 0, 0); \
          acc[h * 4 + j] = __builtin_amdgcn_mfma_f32_16x16x32_bf16(al, bhf[j], acc[h * 4 + j], 0, 0, 0); \
        }                                                                        \
      }                                                                          \
    }                                                                            \
  }

__global__ __launch_bounds__(256, 3) void k_main(const float* __restrict__ x,
                                                 const unsigned short* __restrict__ Bhg,
                                                 const unsigned short* __restrict__ Blg,
                                                 const int* __restrict__ order,
                                                 const int* __restrict__ offsg,
                                                 const float* __restrict__ sume,
                                                 const float* __restrict__ rinv,
                                                 float* __restrict__ idxout,
                                                 float* __restrict__ accg) {
    int q = blockIdx.x;
    int tile = blockIdx.y;
    int base = offsg[q];
    int cnt = offsg[q + 1] - base;
    int tstart = tile * 64;
    if (tstart >= cnt) return;            // block-uniform exit, before any barrier
    int nt = min(64, cnt - tstart);

    __shared__ unsigned short Bls[3][2][4096];   // [buf][plane][8 frags * 512] = 48 KB
    __shared__ int   toks_s[64];
    __shared__ float sume_s[128];
    __shared__ float rinv_s[128];
    __shared__ float redv[64];
    __shared__ int   redi[64];

    int tid = threadIdx.x;
    int lane = tid & 63;
    int wv = tid >> 6;                    // 0..3 = M-wave (16 rows each)
    int lc = lane & 15, q4 = lane >> 4;
    int lane8 = lane * 8;
    int stoff = wv * 1024 + lane8;        // global src offset within a 4096-short chunk
    int ldoff = wv * 1024;                // wave-uniform LDS dest (HW adds lane*16B)

    if (tid < 64) toks_s[tid] = order[base + tstart + min(tid, nt - 1)];
    if (tid < 128) {
        sume_s[tid] = sume[q * PT + tid];
        rinv_s[tid] = rinv[q * PT + tid];
    }

    // A: this lane owns row wv*16+lc, k-segment q4*8 (clamped tail dups last row)
    int rowA = wv * 16 + lc;
    int tokA = order[base + tstart + min(rowA, nt - 1)];
    const float* ap = x + (size_t)tokA * DIM + q4 * 8;

    const unsigned short* bhg = Bhg + (size_t)q * (PT * DIM);
    const unsigned short* blg = Blg + (size_t)q * (PT * DIM);

    floatx4 acc[8];
#pragma unroll
    for (int ni = 0; ni < 8; ni++) acc[ni] = (floatx4){0.f, 0.f, 0.f, 0.f};
    float ps = 0.f;
    float4 Aa[2], Ab[2], Ac[2], Ad[2];

    // prologue (FIFO oldest-first): B0(4), A0(2), B1(4), A1(2), A2(2) = 14 ops
    stage2(bhg + stoff, &Bls[0][0][ldoff]);
    stage2(blg + stoff, &Bls[0][1][ldoff]);
    __builtin_amdgcn_sched_barrier(0);
    Aa[0] = *(const float4*)(ap);       Aa[1] = *(const float4*)(ap + 4);
    __builtin_amdgcn_sched_barrier(0);
    stage2(bhg + 4096 + stoff, &Bls[1][0][ldoff]);
    stage2(blg + 4096 + stoff, &Bls[1][1][ldoff]);
    __builtin_amdgcn_sched_barrier(0);
    Ab[0] = *(const float4*)(ap + 32);  Ab[1] = *(const float4*)(ap + 36);
    __builtin_amdgcn_sched_barrier(0);
    Ac[0] = *(const float4*)(ap + 64);  Ac[1] = *(const float4*)(ap + 68);

    // 16 K-steps. A-set rotation: step S uses set S%4, fills set (S+3)%4.
    KSTEP(0,  "8", Aa, Ad, 1, 1)
    KSTEP(1,  "8", Ab, Aa, 1, 1)
    KSTEP(2,  "8", Ac, Ab, 1, 1)
    KSTEP(3,  "8", Ad, Ac, 1, 1)
    KSTEP(4,  "8", Aa, Ad, 1, 1)
    KSTEP(5,  "8", Ab, Aa, 1, 1)
    KSTEP(6,  "8", Ac, Ab, 1, 1)
    KSTEP(7,  "8", Ad, Ac, 1, 1)
    KSTEP(8,  "8", Aa, Ad, 1, 1)
    KSTEP(9,  "8", Ab, Aa, 1, 1)
    KSTEP(10, "8", Ac, Ab, 1, 1)
    KSTEP(11, "8", Ad, Ac, 1, 1)
    KSTEP(12, "8", Aa, Ad, 1, 1)
    KSTEP(13, "8", Ab, Aa, 1, 0)
    KSTEP(14, "6", Ac, Ab, 0, 0)
    KSTEP(15, "0", Ad, Aa, 0, 0)

    // rnorm: reduce k-segment partials; lane L then holds rn of row wv*16+(L&15)
    ps += __shfl_xor(ps, 16);
    ps += __shfl_xor(ps, 32);
    float rnv = 1.0f / fmaxf(sqrtf(ps), 1e-12f);

    // argmin over all 128 codes (this wave's 16 rows). C/D: col=lc, row=q4*4+reg
#pragma unroll
    for (int r = 0; r < 4; r++) {
        int rowrel = q4 * 4 + r;                       // 0..15
        float rn2v = -2.0f * __shfl(rnv, rowrel);
        float bv = 1e30f; int bc = 0;
#pragma unroll
        for (int ni = 0; ni < 8; ni++) {
            int n = ni * 16 + lc;
            float d = fmaf(rn2v, acc[ni][r], sume_s[n]);
            if (d < bv) { bv = d; bc = n; }            // n ascending: strict < keeps lowest
        }
#pragma unroll
        for (int mk = 1; mk <= 8; mk <<= 1) {          // reduce across 16-lane col group
            float ov = __shfl_xor(bv, mk);
            int oc = __shfl_xor(bc, mk);
            if (ov < bv || (ov == bv && oc < bc)) { bv = ov; bc = oc; }
        }
        int m = wv * 16 + rowrel;                      // 0..63
        if (lc == 0) { redv[m] = bv; redi[m] = bc; }
    }
    __syncthreads();

    // final select per token: idx (global code) + closed-form loss row-sum 2 - 2*sim
    if (tid < 64) {
        int c = redi[tid];
        float bvv = redv[tid];
        float term = 0.0f;
        if (tid < nt) {
            idxout[toks_s[tid]] = (float)(q * PT + c);
            term = 2.0f - (sume_s[c] - bvv) * rinv_s[c];   // bv = sume_c - 2*rn*dot
        }
        for (int mk = 32; mk; mk >>= 1) term += __shfl_xor(term, mk);
        if (tid == 0) atomicAdd(&accg[0], term);
    }
}

// ---------------- k_post: out-writer (blocks 0..511) + ne-based uloss (512..823) +
// finalize via donec among uloss blocks. Out and uloss co-resident -> overlap. ------
__global__ __launch_bounds__(256) void k_post(const float* __restrict__ emb,
                                              const float* __restrict__ rinv,
                                              const float* __restrict__ idxf,
                                              float* __restrict__ outbuf,
                                              const float* __restrict__ ne,
                                              const int* __restrict__ samp,
                                              float* __restrict__ accg,
                                              int* __restrict__ donec,
                                              float* __restrict__ lossp) {
    __shared__ float rs[4], rp[4];
    int bid = blockIdx.x;
    int tid = threadIdx.x, lane = tid & 63, wv = tid >> 6;
    if (bid < NTOK / 64) {
        // token-major sequential 64MB write; emb reads L2/L3-hit; 1-token prefetch
        int tbase = bid * 64 + wv * 16;
        int cL = 0; float rvL = 0.f;
        if (lane < 16) {
            cL = (int)idxf[tbase + lane];
            rvL = rinv[cL];
        }
        const float4* er = (const float4*)emb;
        int c0 = __shfl(cL, 0); float rv0 = __shfl(rvL, 0);
        float4 ea = er[(size_t)c0 * 128 + lane * 2];
        float4 eb = er[(size_t)c0 * 128 + lane * 2 + 1];
#pragma unroll
        for (int t = 0; t < 16; t++) {
            float4 ca = ea, cb = eb;
            float rv = rv0;
            if (t < 15) {
                int c1 = __shfl(cL, t + 1);
                rv0 = __shfl(rvL, t + 1);
                ea = er[(size_t)c1 * 128 + lane * 2];
                eb = er[(size_t)c1 * 128 + lane * 2 + 1];
            }
            float4* orow = (float4*)(outbuf + (size_t)(tbase + t) * DIM);
            orow[lane * 2]     = make_float4(ca.x * rv, ca.y * rv, ca.z * rv, ca.w * rv);
            orow[lane * 2 + 1] = make_float4(cb.x * rv, cb.y * rv, cb.z * rv, cb.w * rv);
        }
    } else {
        // uloss: reads ONLY the 640KB L2-resident ne table
        int i = bid - NTOK / 64;
        int labi = samp[i] >> 7;
        const float4* ri = (const float4*)(ne + (size_t)i * DIM);
        float4 e0 = ri[lane * 2], e1 = ri[lane * 2 + 1];
        float sE = 0.0f, pE = 0.0f;
        for (int j0 = wv; j0 < NSAMP; j0 += 16) {
            float d[4]; int lj[4]; bool val[4];
#pragma unroll
            for (int u = 0; u < 4; u++) {
                int j = j0 + u * 4;
                val[u] = (j < NSAMP) && (j != i);
                int js = val[u] ? j : 0;
                lj[u] = samp[js] >> 7;
                const float4* rj = (const float4*)(ne + (size_t)js * DIM);
                float4 f0 = rj[lane * 2], f1 = rj[lane * 2 + 1];
                d[u] = e0.x*f0.x + e0.y*f0.y + e0.z*f0.z + e0.w*f0.w
                     + e1.x*f1.x + e1.y*f1.y + e1.z*f1.z + e1.w*f1.w;
            }
#pragma unroll
            for (int mk = 32; mk; mk >>= 1)
#pragma unroll
                for (int u = 0; u < 4; u++) d[u] += __shfl_xor(d[u], mk);
#pragma unroll
            for (int u = 0; u < 4; u++) {
                float ex = val[u] ? expf(d[u] * INV_TEMP) : 0.0f;
                sE += ex;
                if (val[u] && lj[u] == labi) pE += ex;
            }
        }
        if (lane == 0) { rs[wv] = sE; rp[wv] = pE; }
        __syncthreads();
        if (tid == 0) {
            float S = rs[0] + rs[1] + rs[2] + rs[3];
            float P = rp[0] + rp[1] + rp[2] + rp[3];
            atomicAdd(&accg[1], logf(S) - logf(P));
            __threadfence();
            int old = atomicAdd(donec, 1);
            if (old == NSAMP - 1) {                    // last uloss block finalizes
                __threadfence();
                float a0 = atomicAdd(&accg[0], 0.0f);  // from k_main (stream-ordered)
                float a1 = atomicAdd(&accg[1], 0.0f);  // adds ordered before donec
                lossp[0] = (1.25f / ((float)NTOK * (float)DIM)) * a0;
                lossp[1] = a1 / (float)NSAMP;
            }
        }
    }
}

extern "C" void kernel_launch(void* const* d_in, const int* in_sizes, int n_in,
                              void* d_out, int out_size, void* d_ws, size_t ws_size,
                              hipStream_t stream) {
    const float* x   = (const float*)d_in[0];
    const float* emb = (const float*)d_in[1];
    const int* Q     = (const int*)d_in[2];
    const int* samp  = (const int*)d_in[3];

    float* out    = (float*)d_out;                       // [NTOK*DIM]
    float* lossp  = out + (size_t)NTOK * DIM;            // loss, uloss
    float* idxout = out + (size_t)NTOK * DIM + 2;        // [NTOK] idx as float

    unsigned short* Bhg = (unsigned short*)d_ws;         // NCODES*DIM bf16-hi (frag-swizzled)
    unsigned short* Blg = Bhg + (size_t)NCODES * DIM;    // NCODES*DIM bf16-lo (frag-swizzled)
    float* sume  = (float*)(Blg + (size_t)NCODES * DIM); // NCODES
    float* rinv  = sume + NCODES;                        // NCODES
    int* bhist   = (int*)(rinv + NCODES);                // 128*32
    int* rankb   = bhist + (NTOK / 256) * 32;            // NTOK
    int* offsg   = rankb + NTOK;                         // NTYPES+1 (pad 32)
    int* order   = offsg + 32;                           // NTOK
    float* ne    = (float*)(order + NTOK);               // NSAMP*DIM f32 (640KB)
    float* accg  = ne + (size_t)NSAMP * DIM;             // [2]
    int* donec   = (int*)(accg + 2);                     // [1]

    k_pre<<<NCODES / 4 + NTOK / 256, 256, 0, stream>>>(emb, Q, Bhg, Blg, sume, rinv,
                                                       bhist, rankb, accg, donec);
    k_scat<<<NTOK / 256 + NSAMP / 4, 256, 0, stream>>>(Q, bhist, rankb, emb, rinv,
                                                       samp, order, offsg, ne);
    dim3 gmain(NTYPES, MAXTILES);
    k_main<<<gmain, 256, 0, stream>>>(x, Bhg, Blg, order, offsg, sume, rinv,
                                      idxout, accg);
    k_post<<<NTOK / 64 + NSAMP, 256, 0, stream>>>(emb, rinv, idxout, out, ne, samp,
                                                  accg, donec, lossp);
}